// Round 2
// baseline (1373.931 us; speedup 1.0000x reference)
//
#include <hip/hip_runtime.h>
#include <math.h>

// MemoryCenters: sim = q·K^T (1024x100000, D=128), top-32 by rbf=exp(-2*dist_sq),
// softmax(log(rbf+eps)+log(h+eps)), r_V = w·V_sel, r_E = w·e_sel.
//
// Round 2: bf16 MFMA filter + exact fp32 rescue.
//   pass1 (MODE 0): bf16 MFMA GEMM q vs first 8192 centers (fp32->bf16 on the fly),
//                   store sims fp32 -> ws
//   thresh:         per-query histogram -> conservative threshold T_q
//   convert:        K,Q fp32 -> bf16 into the (now dead) sims region
//   pass2 (MODE 1): bf16 MFMA GEMM q vs all N, append center idx where
//                   sim_bf16 >= T_q - EPSM  (EPSM covers bf16 dot error, ~520 survivors/q)
//   finalize:       recompute EXACT fp32 sims for survivors, exact sorted top-32
//                   (tie -> lower index, = jax.lax.top_k), weights, V/e gathers.
// ws: 32MB (sims, later Kbf+Qbf) + 8KB + 8MB cidx = 40.008 MB (<= proven 40.014).

#define DDIM    128
#define TILE    128
#define MSAMPLE 8192
#define NBINS   1024
#define CAP     2048
#define TOPK    32
#define NQTOT   1024
#define EPSM    0.02f

typedef __attribute__((ext_vector_type(8))) short short8;   // 8 bf16 = 4 VGPRs (mfma A/B frag)
typedef __attribute__((ext_vector_type(4))) float f32x4;    // mfma C/D frag

// RNE f32 -> bf16 (inputs are finite; no NaN handling needed)
__device__ inline unsigned short f2bf(float f) {
    unsigned u = __builtin_bit_cast(unsigned, f);
    return (unsigned short)((u + 0x7FFFu + ((u >> 16) & 1u)) >> 16);
}

// ---------------------------------------------------------------------------
// fp32 -> bf16 pre-convert of Q then K (contiguous vectorized, grid-stride)
// ---------------------------------------------------------------------------
__global__ __launch_bounds__(256)
void convert_kernel(const float* __restrict__ Qg, const float* __restrict__ Kg,
                    unsigned short* __restrict__ Qbf, unsigned short* __restrict__ Kbf,
                    int nq8, int nk8)
{
    int total = nq8 + nk8;
    for (int i = blockIdx.x * 256 + threadIdx.x; i < total; i += gridDim.x * 256) {
        const float* s; unsigned short* d; int j;
        if (i < nq8) { s = Qg; d = Qbf; j = i; }
        else         { s = Kg; d = Kbf; j = i - nq8; }
        float4 a = *reinterpret_cast<const float4*>(s + (size_t)j * 8);
        float4 b = *reinterpret_cast<const float4*>(s + (size_t)j * 8 + 4);
        short8 o;
        o[0] = (short)f2bf(a.x); o[1] = (short)f2bf(a.y);
        o[2] = (short)f2bf(a.z); o[3] = (short)f2bf(a.w);
        o[4] = (short)f2bf(b.x); o[5] = (short)f2bf(b.y);
        o[6] = (short)f2bf(b.z); o[7] = (short)f2bf(b.w);
        *reinterpret_cast<short8*>(d + (size_t)j * 8) = o;
    }
}

// ---------------------------------------------------------------------------
// bf16 MFMA GEMM, 128x128 tile, 4 waves x (64x64), K-chunk 64, XOR-swizzled LDS.
// MODE 0: fp32 sources (convert in staging), store sims fp32.
// MODE 1: bf16 sources, threshold-append center indices.
// Both A and B tiles are row-major over k with identical per-lane slot rule
// (lane&15 -> row/col, lane>>4 -> k-block), so the k-permutation vs the HW
// wiring cancels between A and B (B^T-input GEMM pattern).
// ---------------------------------------------------------------------------
template<int MODE>
__global__ __launch_bounds__(256)
void gemm_pass(const float* __restrict__ Qf, const float* __restrict__ Kf,
               const unsigned short* __restrict__ Qb, const unsigned short* __restrict__ Kb,
               int N, float* __restrict__ simsOut,
               const float* __restrict__ thr,
               int* __restrict__ cnt, int* __restrict__ cidx)
{
    __shared__ __align__(16) unsigned char As[TILE * 128];  // 128 rows x 64 bf16 = 16KB
    __shared__ __align__(16) unsigned char Bs[TILE * 128];  // 16KB
    const int tid   = threadIdx.x;
    const int lane  = tid & 63;
    const int w     = tid >> 6;
    const int wr    = (w >> 1) * 64;   // wave's row block
    const int wc    = (w & 1) * 64;    // wave's col block
    const int lr    = lane & 15;
    const int lk    = lane >> 4;
    const int cbase = blockIdx.x * TILE;
    const int qbase = blockIdx.y * TILE;

    float thrv[4][4];
    if (MODE == 1) {
        #pragma unroll
        for (int fm = 0; fm < 4; ++fm)
            #pragma unroll
            for (int j = 0; j < 4; ++j)
                thrv[fm][j] = thr[qbase + wr + fm * 16 + lk * 4 + j];
    }

    const f32x4 z = {0.f, 0.f, 0.f, 0.f};
    f32x4 acc[4][4];
    #pragma unroll
    for (int a = 0; a < 4; ++a)
        #pragma unroll
        for (int b = 0; b < 4; ++b) acc[a][b] = z;

    const int sr = tid >> 3;   // staging row 0..31 (+32*rr)
    const int c8 = tid & 7;    // 16B chunk within 128B row

    for (int d0 = 0; d0 < DDIM; d0 += 64) {
        __syncthreads();
        #pragma unroll
        for (int rr = 0; rr < 4; ++rr) {
            int r  = rr * 32 + sr;
            int cb = (c8 * 16) ^ ((r & 7) << 4);      // XOR swizzle (G4)
            short8 qv;
            if (MODE == 0) {
                const float* p = Qf + (size_t)(qbase + r) * DDIM + d0 + c8 * 8;
                float4 x = *reinterpret_cast<const float4*>(p);
                float4 y = *reinterpret_cast<const float4*>(p + 4);
                qv[0]=(short)f2bf(x.x); qv[1]=(short)f2bf(x.y);
                qv[2]=(short)f2bf(x.z); qv[3]=(short)f2bf(x.w);
                qv[4]=(short)f2bf(y.x); qv[5]=(short)f2bf(y.y);
                qv[6]=(short)f2bf(y.z); qv[7]=(short)f2bf(y.w);
            } else {
                qv = *reinterpret_cast<const short8*>(Qb + (size_t)(qbase + r) * DDIM + d0 + c8 * 8);
            }
            *reinterpret_cast<short8*>(As + r * 128 + cb) = qv;

            int row = cbase + r;
            short8 kv = {0,0,0,0,0,0,0,0};
            if (MODE == 0) {           // MSAMPLE rows always in range
                const float* p = Kf + (size_t)row * DDIM + d0 + c8 * 8;
                float4 x = *reinterpret_cast<const float4*>(p);
                float4 y = *reinterpret_cast<const float4*>(p + 4);
                kv[0]=(short)f2bf(x.x); kv[1]=(short)f2bf(x.y);
                kv[2]=(short)f2bf(x.z); kv[3]=(short)f2bf(x.w);
                kv[4]=(short)f2bf(y.x); kv[5]=(short)f2bf(y.y);
                kv[6]=(short)f2bf(y.z); kv[7]=(short)f2bf(y.w);
            } else if (row < N) {
                kv = *reinterpret_cast<const short8*>(Kb + (size_t)row * DDIM + d0 + c8 * 8);
            }
            *reinterpret_cast<short8*>(Bs + r * 128 + cb) = kv;
        }
        __syncthreads();
        #pragma unroll
        for (int ks = 0; ks < 2; ++ks) {
            short8 af[4], bg[4];
            #pragma unroll
            for (int f = 0; f < 4; ++f) {
                int ra = wr + f * 16 + lr;
                int ca = (ks * 64 + lk * 16) ^ ((ra & 7) << 4);
                af[f] = *reinterpret_cast<const short8*>(As + ra * 128 + ca);
                int rb = wc + f * 16 + lr;
                int cb2 = (ks * 64 + lk * 16) ^ ((rb & 7) << 4);
                bg[f] = *reinterpret_cast<const short8*>(Bs + rb * 128 + cb2);
            }
            #pragma unroll
            for (int fm = 0; fm < 4; ++fm)
                #pragma unroll
                for (int fn = 0; fn < 4; ++fn)
                    acc[fm][fn] = __builtin_amdgcn_mfma_f32_16x16x32_bf16(
                        af[fm], bg[fn], acc[fm][fn], 0, 0, 0);
        }
    }

    // epilogue — C/D mapping: col = lane&15, row = (lane>>4)*4 + reg  [m89/m91]
    #pragma unroll
    for (int fm = 0; fm < 4; ++fm) {
        #pragma unroll
        for (int j = 0; j < 4; ++j) {
            int q = qbase + wr + fm * 16 + lk * 4 + j;
            #pragma unroll
            for (int fn = 0; fn < 4; ++fn) {
                int c   = cbase + wc + fn * 16 + lr;
                float s = acc[fm][fn][j];
                if (MODE == 0) {
                    simsOut[(size_t)q * MSAMPLE + c] = s;
                } else {
                    if (c < N && s >= thrv[fm][j] - EPSM) {
                        int p = atomicAdd(&cnt[q], 1);
                        if (p < CAP) cidx[(size_t)q * CAP + p] = c;
                    }
                }
            }
        }
    }
}

// ---------------------------------------------------------------------------
// Per-query threshold: histogram + suffix-sum; T = lower edge of the bin
// holding the 32nd-largest sample sim, minus one bin.
// ---------------------------------------------------------------------------
__global__ __launch_bounds__(256)
void thresh_kernel(const float* __restrict__ sims, float* __restrict__ thr)
{
    __shared__ int hA[NBINS];
    __shared__ int hB[NBINS];
    __shared__ int best;
    const int q = blockIdx.x, tid = threadIdx.x;
    for (int i = tid; i < NBINS; i += 256) hA[i] = 0;
    if (tid == 0) best = 0;
    __syncthreads();
    for (int i = tid; i < MSAMPLE; i += 256) {
        float s = sims[(size_t)q * MSAMPLE + i];
        int b = (int)((s + 1.0f) * (NBINS * 0.5f));
        b = b < 0 ? 0 : (b > NBINS - 1 ? NBINS - 1 : b);
        atomicAdd(&hA[b], 1);
    }
    __syncthreads();
    int* src = hA; int* dst = hB;
    for (int off = 1; off < NBINS; off <<= 1) {
        for (int i = tid; i < NBINS; i += 256)
            dst[i] = src[i] + ((i + off < NBINS) ? src[i + off] : 0);
        __syncthreads();
        int* tmp = src; src = dst; dst = tmp;
    }
    for (int i = tid; i < NBINS; i += 256)
        if (src[i] >= TOPK) atomicMax(&best, i);
    __syncthreads();
    if (tid == 0)
        thr[q] = (float)(best - 1) * (2.0f / NBINS) - 1.0f;
}

// ---------------------------------------------------------------------------
// Finalize: EXACT fp32 sims for survivors, exact sorted top-32 (tie -> lower
// index), softmax weights, V/e gathers, write all 4 outputs.
// ---------------------------------------------------------------------------
__global__ __launch_bounds__(256)
void finalize_kernel(const int* __restrict__ cidx, const int* __restrict__ cnt,
                     const float* __restrict__ Qg, const float* __restrict__ Kg,
                     const float* __restrict__ V, const float* __restrict__ hIn,
                     const float* __restrict__ eIn,
                     float* __restrict__ out, int N)
{
    __shared__ float qv[DDIM];
    __shared__ float rv[CAP];
    __shared__ int   ri[CAP];
    __shared__ float selV[TOPK];
    __shared__ int   selI[TOPK];
    __shared__ float wts[TOPK];
    const int q = blockIdx.x, tid = threadIdx.x;
    const int n = min(cnt[q], CAP);
    if (tid < DDIM) qv[tid] = Qg[(size_t)q * DDIM + tid];
    __syncthreads();
    for (int i = tid; i < CAP; i += 256) {
        if (i < n) {
            int c = cidx[(size_t)q * CAP + i];
            const float4* kr = reinterpret_cast<const float4*>(Kg + (size_t)c * DDIM);
            float s = 0.f;
            #pragma unroll
            for (int d4 = 0; d4 < DDIM / 4; ++d4) {
                float4 kk = kr[d4];
                float4 qq = *reinterpret_cast<const float4*>(qv + 4 * d4);
                s = fmaf(qq.x, kk.x, s); s = fmaf(qq.y, kk.y, s);
                s = fmaf(qq.z, kk.z, s); s = fmaf(qq.w, kk.w, s);
            }
            float dist = 2.0f - 2.0f * s;        // match reference op order
            rv[i] = expf(dist * -2.0f);          // exp(-dist/(2*0.25))
            ri[i] = c;
        } else { rv[i] = -1.0f; ri[i] = 0; }
    }
    __syncthreads();
    if (tid < 64) {
        for (int r = 0; r < TOPK; ++r) {
            float bv = -1.0f; int bi = 0x7fffffff; int bp = -1;
            for (int i = tid; i < n; i += 64) {
                float v = rv[i]; int ix = ri[i];
                if (v > bv || (v == bv && ix < bi)) { bv = v; bi = ix; bp = i; }
            }
            #pragma unroll
            for (int o = 32; o > 0; o >>= 1) {
                float ov = __shfl_down(bv, o);
                int   oi = __shfl_down(bi, o);
                int   op = __shfl_down(bp, o);
                if (ov > bv || (ov == bv && oi < bi)) { bv = ov; bi = oi; bp = op; }
            }
            bp = __shfl(bp, 0);
            if (tid == 0) { selV[r] = bv; selI[r] = bi; }
            if (bp >= 0 && (bp & 63) == tid) rv[bp] = -1.0f;  // only this lane rescans slot bp
        }
    }
    __syncthreads();
    if (tid < TOPK) {
        float lw = logf(selV[tid] + 1e-8f) + logf(hIn[selI[tid]] + 1e-8f);
        float mx = lw;
        #pragma unroll
        for (int o = 16; o > 0; o >>= 1) mx = fmaxf(mx, __shfl_xor(mx, o));
        float ex = expf(lw - mx);
        float sm = ex;
        #pragma unroll
        for (int o = 16; o > 0; o >>= 1) sm += __shfl_xor(sm, o);
        wts[tid] = ex / sm;
    }
    __syncthreads();
    {
        float acc = 0.f;
        const int v = tid;
        #pragma unroll 8
        for (int k = 0; k < TOPK; ++k)
            acc = fmaf(wts[k], V[(size_t)selI[k] * 256 + v], acc);
        out[(size_t)q * 256 + v] = acc;
    }
    const int offE = NQTOT * 256;
    const int offW = offE + NQTOT * 4;
    const int offI = offW + NQTOT * TOPK;
    if (tid < 4) {
        float acc = 0.f;
        for (int k = 0; k < TOPK; ++k)
            acc = fmaf(wts[k], eIn[(size_t)selI[k] * 4 + tid], acc);
        out[offE + q * 4 + tid] = acc;
    }
    if (tid < TOPK) {
        out[offW + q * TOPK + tid] = wts[tid];
        out[offI + q * TOPK + tid] = (float)selI[tid];
    }
}

// ---------------------------------------------------------------------------
extern "C" void kernel_launch(void* const* d_in, const int* in_sizes, int n_in,
                              void* d_out, int out_size, void* d_ws, size_t ws_size,
                              hipStream_t stream)
{
    (void)n_in; (void)out_size; (void)ws_size;
    const float* Qg = (const float*)d_in[0];
    const float* Kg = (const float*)d_in[1];
    const float* Vg = (const float*)d_in[2];
    const float* hg = (const float*)d_in[3];
    const float* eg = (const float*)d_in[4];
    const int N = in_sizes[1] / DDIM;          // 100000

    char* w = (char*)d_ws;
    float* sims = (float*)w;                                        // 32MB, live pass1->thresh
    unsigned short* Kbf = (unsigned short*)w;                       // reuses sims region
    unsigned short* Qbf = (unsigned short*)(w + (size_t)N * DDIM * 2);  // +25.6MB (within 32MB)
    w += (size_t)NQTOT * MSAMPLE * 4;                               // 32MB
    float* thr = (float*)w;  w += NQTOT * 4;
    int*   cnt = (int*)w;    w += NQTOT * 4;
    int*   cidx = (int*)w;                                          // 8MB

    hipMemsetAsync(cnt, 0, NQTOT * 4, stream);

    dim3 blk(256);
    gemm_pass<0><<<dim3(MSAMPLE / TILE, NQTOT / TILE), blk, 0, stream>>>(
        Qg, Kg, nullptr, nullptr, N, sims, nullptr, nullptr, nullptr);
    thresh_kernel<<<dim3(NQTOT), blk, 0, stream>>>(sims, thr);
    convert_kernel<<<dim3(2048), blk, 0, stream>>>(
        Qg, Kg, Qbf, Kbf, NQTOT * DDIM / 8, N * DDIM / 8);
    gemm_pass<1><<<dim3((N + TILE - 1) / TILE, NQTOT / TILE), blk, 0, stream>>>(
        nullptr, nullptr, Qbf, Kbf, N, nullptr, thr, cnt, cidx);
    finalize_kernel<<<dim3(NQTOT), blk, 0, stream>>>(
        cidx, cnt, Qg, Kg, Vg, hg, eg, (float*)d_out, N);
}

// Round 4
// 234.825 us; speedup vs baseline: 5.8509x; 5.8509x over previous
//
#include <hip/hip_runtime.h>
#include <math.h>

// MemoryCenters: sim = q·K^T (1024x100000, D=128), top-32 by rbf=exp(-2*dist_sq),
// softmax(log(rbf+eps)+log(h+eps)), r_V = w·V_sel, r_E = w·e_sel.
//
// Round 4 = Round 3 with the u8-bin wrap bug fixed (NBINS 1024 -> 256 so bins fit
// in a byte; EPSM 0.006 -> 0.012 for bf16 completeness margin).
//   convert: Q,K fp32 -> bf16
//   pass1 (MODE 0): bf16 MFMA GEMM q vs first 12288 centers -> u8 bin (256 bins) per sim
//   thresh: per-query histogram of bins -> conservative threshold T_q
//           (lower edge of bin holding 32nd-largest sample sim, minus one bin)
//   pass2 (MODE 1): grid (64 groups x 8 qtiles); block owns center-group g exclusively,
//                   loops ~12 center tiles with A(Q)-tile LDS-resident; survivors
//                   (sim_bf16 >= T_q - EPSM, ~620/query) appended to buckets[q][g][48]
//                   via LDS-local atomics + plain global stores. NO cross-block atomics.
//   finalize: compact buckets, recompute EXACT fp32 sims, exact sorted top-32
//             (rbf desc, tie -> lower index = jax.lax.top_k), weights, V/e gathers.
// ws: 25.6MB Kbf + 256KB Qbf + 4KB thr + 256KB cnt2 + 12.58MB (binsU8 | buckets) = 38.7MB.

#define DDIM    128
#define MSAMPLE 12288
#define NBINS   256
#define TOPK    32
#define NQTOT   1024
#define NGRP    64
#define BCAP    48
#define EPSM    0.012f

typedef __attribute__((ext_vector_type(8))) short short8;   // 8 bf16 = 4 VGPRs
typedef __attribute__((ext_vector_type(4))) float f32x4;    // mfma C/D frag

__device__ inline unsigned short f2bf(float f) {
    unsigned u = __builtin_bit_cast(unsigned, f);
    return (unsigned short)((u + 0x7FFFu + ((u >> 16) & 1u)) >> 16);
}

// ---------------------------------------------------------------------------
__global__ __launch_bounds__(256)
void convert_kernel(const float* __restrict__ Qg, const float* __restrict__ Kg,
                    unsigned short* __restrict__ Qbf, unsigned short* __restrict__ Kbf,
                    int nq8, int nk8)
{
    int total = nq8 + nk8;
    for (int i = blockIdx.x * 256 + threadIdx.x; i < total; i += gridDim.x * 256) {
        const float* s; unsigned short* d; int j;
        if (i < nq8) { s = Qg; d = Qbf; j = i; }
        else         { s = Kg; d = Kbf; j = i - nq8; }
        float4 a = *reinterpret_cast<const float4*>(s + (size_t)j * 8);
        float4 b = *reinterpret_cast<const float4*>(s + (size_t)j * 8 + 4);
        short8 o;
        o[0] = (short)f2bf(a.x); o[1] = (short)f2bf(a.y);
        o[2] = (short)f2bf(a.z); o[3] = (short)f2bf(a.w);
        o[4] = (short)f2bf(b.x); o[5] = (short)f2bf(b.y);
        o[6] = (short)f2bf(b.z); o[7] = (short)f2bf(b.w);
        *reinterpret_cast<short8*>(d + (size_t)j * 8) = o;
    }
}

// ---------------------------------------------------------------------------
// bf16 MFMA GEMM, 128x128 tile, full K=128 staged, 4 waves x (64x64),
// XOR-swizzled LDS (proven conflict-free in R2). A-tile resident across t-loop.
// MODE 0: write u8 bins for sample sims. MODE 1: bucket-append survivors.
// ---------------------------------------------------------------------------
template<int MODE>
__global__ __launch_bounds__(256)
void gemm_pass(const unsigned short* __restrict__ Qb, const unsigned short* __restrict__ Kb,
               int N, unsigned char* __restrict__ binsU8,
               const float* __restrict__ thr,
               int* __restrict__ cnt2, unsigned int* __restrict__ buckets)
{
    __shared__ __align__(16) unsigned char As[128 * 256];  // 128 q x 128 bf16 = 32KB
    __shared__ __align__(16) unsigned char Bs[128 * 256];  // 32KB
    __shared__ int off_l[128];
    const int tid   = threadIdx.x;
    const int lane  = tid & 63;
    const int w     = tid >> 6;
    const int wr    = (w >> 1) * 64;
    const int wc    = (w & 1) * 64;
    const int lr    = lane & 15;
    const int lk    = lane >> 4;          // 0..3
    const int g     = blockIdx.x;
    const int qbase = blockIdx.y * 128;

    int t0, tcnt;
    if (MODE == 0) { t0 = g; tcnt = 1; }                    // 96 tiles of samples
    else { t0 = g * 12 + min(g, 14); tcnt = 12 + (g < 14 ? 1 : 0); }  // 782 tiles

    if (MODE == 1)
        for (int i = tid; i < 128; i += 256) off_l[i] = 0;

    // stage A once (full K), swizzled
    #pragma unroll
    for (int it = 0; it < 8; ++it) {
        int flat = it * 256 + tid;
        int r = flat >> 4, cc = flat & 15;
        short8 v = *reinterpret_cast<const short8*>(
            Qb + (size_t)(qbase + r) * DDIM + cc * 8);
        *reinterpret_cast<short8*>(As + r * 256 + ((cc ^ (r & 7)) << 4)) = v;
    }

    float thrv[4][4];
    if (MODE == 1) {
        #pragma unroll
        for (int fm = 0; fm < 4; ++fm)
            #pragma unroll
            for (int j = 0; j < 4; ++j)
                thrv[fm][j] = thr[qbase + wr + fm * 16 + lk * 4 + j] - EPSM;
    }

    for (int t = 0; t < tcnt; ++t) {
        const int cbase = (t0 + t) * 128;
        __syncthreads();
        #pragma unroll
        for (int it = 0; it < 8; ++it) {
            int flat = it * 256 + tid;
            int r = flat >> 4, cc = flat & 15;
            int row = cbase + r;
            short8 v = {0,0,0,0,0,0,0,0};
            if (MODE == 0 || row < N)
                v = *reinterpret_cast<const short8*>(
                    Kb + (size_t)row * DDIM + cc * 8);
            *reinterpret_cast<short8*>(Bs + r * 256 + ((cc ^ (r & 7)) << 4)) = v;
        }
        __syncthreads();

        const f32x4 z = {0.f, 0.f, 0.f, 0.f};
        f32x4 acc[4][4];
        #pragma unroll
        for (int a = 0; a < 4; ++a)
            #pragma unroll
            for (int b = 0; b < 4; ++b) acc[a][b] = z;

        #pragma unroll
        for (int ks = 0; ks < 4; ++ks) {
            short8 af[4], bg[4];
            #pragma unroll
            for (int f = 0; f < 4; ++f) {
                int ra = wr + f * 16 + lr;
                af[f] = *reinterpret_cast<const short8*>(
                    As + ra * 256 + (((ks * 4 + lk) ^ (ra & 7)) << 4));
                int rb = wc + f * 16 + lr;
                bg[f] = *reinterpret_cast<const short8*>(
                    Bs + rb * 256 + (((ks * 4 + lk) ^ (rb & 7)) << 4));
            }
            #pragma unroll
            for (int fm = 0; fm < 4; ++fm)
                #pragma unroll
                for (int fn = 0; fn < 4; ++fn)
                    acc[fm][fn] = __builtin_amdgcn_mfma_f32_16x16x32_bf16(
                        af[fm], bg[fn], acc[fm][fn], 0, 0, 0);
        }

        // epilogue — C/D map: col = lane&15, row = (lane>>4)*4 + reg [m89/m91]
        #pragma unroll
        for (int fm = 0; fm < 4; ++fm) {
            #pragma unroll
            for (int j = 0; j < 4; ++j) {
                const int ql = wr + fm * 16 + lk * 4 + j;
                #pragma unroll
                for (int fn = 0; fn < 4; ++fn) {
                    const int c = cbase + wc + fn * 16 + lr;
                    float s = acc[fm][fn][j];
                    if (MODE == 0) {
                        int b = (int)((s + 1.0f) * (NBINS * 0.5f));   // 256 bins over [-1,1]
                        b = b < 0 ? 0 : (b > NBINS - 1 ? NBINS - 1 : b);
                        binsU8[(size_t)(qbase + ql) * MSAMPLE + c] = (unsigned char)b;
                    } else {
                        if (c < N && s >= thrv[fm][j]) {
                            int p = atomicAdd(&off_l[ql], 1);   // LDS-local only
                            if (p < BCAP)
                                buckets[((size_t)(qbase + ql) * NGRP + g) * BCAP + p] =
                                    (unsigned int)c;
                        }
                    }
                }
            }
        }
    }
    if (MODE == 1) {
        __syncthreads();
        for (int i = tid; i < 128; i += 256)
            cnt2[(qbase + i) * NGRP + g] = min(off_l[i], BCAP);
    }
}

// ---------------------------------------------------------------------------
__global__ __launch_bounds__(256)
void thresh_kernel(const unsigned char* __restrict__ bins, float* __restrict__ thr)
{
    __shared__ int hA[NBINS];
    __shared__ int hB[NBINS];
    __shared__ int best;
    const int q = blockIdx.x, tid = threadIdx.x;
    for (int i = tid; i < NBINS; i += 256) hA[i] = 0;
    if (tid == 0) best = 0;
    __syncthreads();
    const uint4* bp = reinterpret_cast<const uint4*>(bins + (size_t)q * MSAMPLE);
    for (int i = tid; i < MSAMPLE / 16; i += 256) {
        uint4 v = bp[i];
        unsigned xs[4] = {v.x, v.y, v.z, v.w};
        #pragma unroll
        for (int k = 0; k < 4; ++k) {
            unsigned x = xs[k];
            atomicAdd(&hA[x & 255], 1); x >>= 8;
            atomicAdd(&hA[x & 255], 1); x >>= 8;
            atomicAdd(&hA[x & 255], 1); x >>= 8;
            atomicAdd(&hA[x & 255], 1);
        }
    }
    __syncthreads();
    int* src = hA; int* dst = hB;
    for (int off = 1; off < NBINS; off <<= 1) {
        for (int i = tid; i < NBINS; i += 256)
            dst[i] = src[i] + ((i + off < NBINS) ? src[i + off] : 0);
        __syncthreads();
        int* tmp = src; src = dst; dst = tmp;
    }
    for (int i = tid; i < NBINS; i += 256)
        if (src[i] >= TOPK) atomicMax(&best, i);
    __syncthreads();
    if (tid == 0)
        thr[q] = (float)(best - 1) * (2.0f / NBINS) - 1.0f;
}

// ---------------------------------------------------------------------------
__global__ __launch_bounds__(256)
void finalize_kernel(const unsigned int* __restrict__ buckets, const int* __restrict__ cnt2,
                     const float* __restrict__ Qg, const float* __restrict__ Kg,
                     const float* __restrict__ V, const float* __restrict__ hIn,
                     const float* __restrict__ eIn,
                     float* __restrict__ out, int N)
{
    __shared__ float qv[DDIM];
    __shared__ float rv[NGRP * BCAP];      // 3072
    __shared__ int   ri[NGRP * BCAP];
    __shared__ int   cnts[NGRP], offs[NGRP];
    __shared__ int   ntot;
    __shared__ float selV[TOPK];
    __shared__ int   selI[TOPK];
    __shared__ float wts[TOPK];
    const int q = blockIdx.x, tid = threadIdx.x;

    if (tid < DDIM) qv[tid] = Qg[(size_t)q * DDIM + tid];
    if (tid < NGRP) cnts[tid] = cnt2[q * NGRP + tid];
    __syncthreads();
    if (tid < NGRP) {
        int c = cnts[tid];
        int x = c;
        #pragma unroll
        for (int o = 1; o < NGRP; o <<= 1) {
            int y = __shfl_up(x, o);
            if (tid >= o) x += y;
        }
        offs[tid] = x - c;
        if (tid == NGRP - 1) ntot = x;
    }
    __syncthreads();
    const int n = ntot;
    for (int flat = tid; flat < NGRP * BCAP; flat += 256) {
        int gg = flat / BCAP, j = flat - gg * BCAP;
        if (j < cnts[gg])
            ri[offs[gg] + j] = (int)buckets[((size_t)q * NGRP + gg) * BCAP + j];
    }
    __syncthreads();
    // exact fp32 sims: 8 lanes per candidate, 32 candidates per sweep
    const int sub = tid & 7, ci = tid >> 3;
    for (int base = 0; base < n; base += 32) {
        int i = base + ci;
        float s = 0.f;
        if (i < n) {
            const float4* k4 = reinterpret_cast<const float4*>(
                Kg + (size_t)ri[i] * DDIM + sub * 16);
            const float4* q4 = reinterpret_cast<const float4*>(qv + sub * 16);
            #pragma unroll
            for (int d = 0; d < 4; ++d) {
                float4 kk = k4[d], qq = q4[d];
                s = fmaf(qq.x, kk.x, s); s = fmaf(qq.y, kk.y, s);
                s = fmaf(qq.z, kk.z, s); s = fmaf(qq.w, kk.w, s);
            }
        }
        s += __shfl_xor(s, 1); s += __shfl_xor(s, 2); s += __shfl_xor(s, 4);
        if (i < n && sub == 0) {
            float dist = 2.0f - 2.0f * s;          // reference op order
            rv[i] = expf(dist * -2.0f);            // exp(-dist/(2*0.25))
        }
    }
    __syncthreads();
    // wave 0: 32 rounds of argmax (rbf desc, tie -> lower index)
    if (tid < 64) {
        for (int r = 0; r < TOPK; ++r) {
            float bv = -1.0f; int bi = 0x7fffffff; int bp = -1;
            for (int i = tid; i < n; i += 64) {
                float v = rv[i]; int ix = ri[i];
                if (v > bv || (v == bv && ix < bi)) { bv = v; bi = ix; bp = i; }
            }
            #pragma unroll
            for (int o = 32; o > 0; o >>= 1) {
                float ov = __shfl_down(bv, o);
                int   oi = __shfl_down(bi, o);
                int   op = __shfl_down(bp, o);
                if (ov > bv || (ov == bv && oi < bi)) { bv = ov; bi = oi; bp = op; }
            }
            bp = __shfl(bp, 0);
            if (tid == 0) { selV[r] = bv; selI[r] = bi; }
            if (bp >= 0 && (bp & 63) == tid) rv[bp] = -1.0f;  // same-lane rescan only
        }
    }
    __syncthreads();
    if (tid < TOPK) {
        float lw = logf(selV[tid] + 1e-8f) + logf(hIn[selI[tid]] + 1e-8f);
        float mx = lw;
        #pragma unroll
        for (int o = 16; o > 0; o >>= 1) mx = fmaxf(mx, __shfl_xor(mx, o));
        float ex = expf(lw - mx);
        float sm = ex;
        #pragma unroll
        for (int o = 16; o > 0; o >>= 1) sm += __shfl_xor(sm, o);
        wts[tid] = ex / sm;
    }
    __syncthreads();
    {
        float acc = 0.f;
        const int v = tid;
        #pragma unroll 8
        for (int k = 0; k < TOPK; ++k)
            acc = fmaf(wts[k], V[(size_t)selI[k] * 256 + v], acc);
        out[(size_t)q * 256 + v] = acc;
    }
    const int offE = NQTOT * 256;
    const int offW = offE + NQTOT * 4;
    const int offI = offW + NQTOT * TOPK;
    if (tid < 4) {
        float acc = 0.f;
        for (int k = 0; k < TOPK; ++k)
            acc = fmaf(wts[k], eIn[(size_t)selI[k] * 4 + tid], acc);
        out[offE + q * 4 + tid] = acc;
    }
    if (tid < TOPK) {
        out[offW + q * TOPK + tid] = wts[tid];
        out[offI + q * TOPK + tid] = (float)selI[tid];
    }
}

// ---------------------------------------------------------------------------
extern "C" void kernel_launch(void* const* d_in, const int* in_sizes, int n_in,
                              void* d_out, int out_size, void* d_ws, size_t ws_size,
                              hipStream_t stream)
{
    (void)n_in; (void)out_size; (void)ws_size;
    const float* Qg = (const float*)d_in[0];
    const float* Kg = (const float*)d_in[1];
    const float* Vg = (const float*)d_in[2];
    const float* hg = (const float*)d_in[3];
    const float* eg = (const float*)d_in[4];
    const int N = in_sizes[1] / DDIM;          // 100000

    char* w = (char*)d_ws;
    unsigned short* Kbf = (unsigned short*)w;  w += (size_t)N * DDIM * 2;      // 25.6MB
    unsigned short* Qbf = (unsigned short*)w;  w += (size_t)NQTOT * DDIM * 2;  // 256KB
    float* thr = (float*)w;                    w += NQTOT * 4;                 // 4KB
    int*   cnt2 = (int*)w;                     w += (size_t)NQTOT * NGRP * 4;  // 256KB
    unsigned char* binsU8 = (unsigned char*)w;                                 // 12.58MB
    unsigned int*  buckets = (unsigned int*)w; // aliases binsU8 (sequential lifetimes)

    hipMemsetAsync(cnt2, 0, (size_t)NQTOT * NGRP * 4, stream);

    dim3 blk(256);
    convert_kernel<<<dim3(2048), blk, 0, stream>>>(
        Qg, Kg, Qbf, Kbf, NQTOT * DDIM / 8, N * DDIM / 8);
    gemm_pass<0><<<dim3(MSAMPLE / 128, NQTOT / 128), blk, 0, stream>>>(
        Qbf, Kbf, N, binsU8, nullptr, nullptr, nullptr);
    thresh_kernel<<<dim3(NQTOT), blk, 0, stream>>>(binsU8, thr);
    gemm_pass<1><<<dim3(NGRP, NQTOT / 128), blk, 0, stream>>>(
        Qbf, Kbf, N, nullptr, thr, cnt2, buckets);
    finalize_kernel<<<dim3(NQTOT), blk, 0, stream>>>(
        buckets, cnt2, Qg, Kg, Vg, hg, eg, (float*)d_out, N);
}

// Round 5
// 204.881 us; speedup vs baseline: 6.7060x; 1.1462x over previous
//
#include <hip/hip_runtime.h>
#include <math.h>

// MemoryCenters: sim = q·K^T (1024x100000, D=128), top-32 by rbf=exp(-2*dist_sq),
// softmax(log(rbf+eps)+log(h+eps)), r_V = w·V_sel, r_E = w·e_sel.
//
// Round 5 = Round 4 with finalize restructured (serial 32-round argmax -> one
// 1024-wide bitonic sort on u64 keys using all 4 waves; wider exact-sim sweep)
// and per-wave sub-histograms in thresh. GEMM/convert identical to passing R4.
//   convert: Q,K fp32 -> bf16
//   pass1 (MODE 0): bf16 MFMA GEMM q vs first 12288 centers -> u8 bin (256 bins)
//   thresh: per-query histogram -> conservative threshold T_q
//   pass2 (MODE 1): 64 exclusive center-groups x 8 qtiles; LDS-local bucket append
//   finalize: compact, exact fp32 rbf, bitonic sort (rbf desc, idx asc =
//             jax.lax.top_k order), weights, V/e gathers.
// ws: 25.6MB Kbf + 256KB Qbf + 4KB thr + 256KB cnt2 + 12.58MB (binsU8|buckets).

#define DDIM    128
#define MSAMPLE 12288
#define NBINS   256
#define TOPK    32
#define NQTOT   1024
#define NGRP    64
#define BCAP    48
#define EPSM    0.012f
#define SORTN   1024

typedef __attribute__((ext_vector_type(8))) short short8;   // 8 bf16 = 4 VGPRs
typedef __attribute__((ext_vector_type(4))) float f32x4;    // mfma C/D frag

__device__ inline unsigned short f2bf(float f) {
    unsigned u = __builtin_bit_cast(unsigned, f);
    return (unsigned short)((u + 0x7FFFu + ((u >> 16) & 1u)) >> 16);
}

// ---------------------------------------------------------------------------
__global__ __launch_bounds__(256)
void convert_kernel(const float* __restrict__ Qg, const float* __restrict__ Kg,
                    unsigned short* __restrict__ Qbf, unsigned short* __restrict__ Kbf,
                    int nq8, int nk8)
{
    int total = nq8 + nk8;
    for (int i = blockIdx.x * 256 + threadIdx.x; i < total; i += gridDim.x * 256) {
        const float* s; unsigned short* d; int j;
        if (i < nq8) { s = Qg; d = Qbf; j = i; }
        else         { s = Kg; d = Kbf; j = i - nq8; }
        float4 a = *reinterpret_cast<const float4*>(s + (size_t)j * 8);
        float4 b = *reinterpret_cast<const float4*>(s + (size_t)j * 8 + 4);
        short8 o;
        o[0] = (short)f2bf(a.x); o[1] = (short)f2bf(a.y);
        o[2] = (short)f2bf(a.z); o[3] = (short)f2bf(a.w);
        o[4] = (short)f2bf(b.x); o[5] = (short)f2bf(b.y);
        o[6] = (short)f2bf(b.z); o[7] = (short)f2bf(b.w);
        *reinterpret_cast<short8*>(d + (size_t)j * 8) = o;
    }
}

// ---------------------------------------------------------------------------
// bf16 MFMA GEMM, 128x128 tile, full K=128 staged, 4 waves x (64x64),
// XOR-swizzled LDS. A-tile resident across t-loop. (identical to R4)
// ---------------------------------------------------------------------------
template<int MODE>
__global__ __launch_bounds__(256)
void gemm_pass(const unsigned short* __restrict__ Qb, const unsigned short* __restrict__ Kb,
               int N, unsigned char* __restrict__ binsU8,
               const float* __restrict__ thr,
               int* __restrict__ cnt2, unsigned int* __restrict__ buckets)
{
    __shared__ __align__(16) unsigned char As[128 * 256];
    __shared__ __align__(16) unsigned char Bs[128 * 256];
    __shared__ int off_l[128];
    const int tid   = threadIdx.x;
    const int lane  = tid & 63;
    const int w     = tid >> 6;
    const int wr    = (w >> 1) * 64;
    const int wc    = (w & 1) * 64;
    const int lr    = lane & 15;
    const int lk    = lane >> 4;
    const int g     = blockIdx.x;
    const int qbase = blockIdx.y * 128;

    int t0, tcnt;
    if (MODE == 0) { t0 = g; tcnt = 1; }
    else { t0 = g * 12 + min(g, 14); tcnt = 12 + (g < 14 ? 1 : 0); }

    if (MODE == 1)
        for (int i = tid; i < 128; i += 256) off_l[i] = 0;

    #pragma unroll
    for (int it = 0; it < 8; ++it) {
        int flat = it * 256 + tid;
        int r = flat >> 4, cc = flat & 15;
        short8 v = *reinterpret_cast<const short8*>(
            Qb + (size_t)(qbase + r) * DDIM + cc * 8);
        *reinterpret_cast<short8*>(As + r * 256 + ((cc ^ (r & 7)) << 4)) = v;
    }

    float thrv[4][4];
    if (MODE == 1) {
        #pragma unroll
        for (int fm = 0; fm < 4; ++fm)
            #pragma unroll
            for (int j = 0; j < 4; ++j)
                thrv[fm][j] = thr[qbase + wr + fm * 16 + lk * 4 + j] - EPSM;
    }

    for (int t = 0; t < tcnt; ++t) {
        const int cbase = (t0 + t) * 128;
        __syncthreads();
        #pragma unroll
        for (int it = 0; it < 8; ++it) {
            int flat = it * 256 + tid;
            int r = flat >> 4, cc = flat & 15;
            int row = cbase + r;
            short8 v = {0,0,0,0,0,0,0,0};
            if (MODE == 0 || row < N)
                v = *reinterpret_cast<const short8*>(
                    Kb + (size_t)row * DDIM + cc * 8);
            *reinterpret_cast<short8*>(Bs + r * 256 + ((cc ^ (r & 7)) << 4)) = v;
        }
        __syncthreads();

        const f32x4 z = {0.f, 0.f, 0.f, 0.f};
        f32x4 acc[4][4];
        #pragma unroll
        for (int a = 0; a < 4; ++a)
            #pragma unroll
            for (int b = 0; b < 4; ++b) acc[a][b] = z;

        #pragma unroll
        for (int ks = 0; ks < 4; ++ks) {
            short8 af[4], bg[4];
            #pragma unroll
            for (int f = 0; f < 4; ++f) {
                int ra = wr + f * 16 + lr;
                af[f] = *reinterpret_cast<const short8*>(
                    As + ra * 256 + (((ks * 4 + lk) ^ (ra & 7)) << 4));
                int rb = wc + f * 16 + lr;
                bg[f] = *reinterpret_cast<const short8*>(
                    Bs + rb * 256 + (((ks * 4 + lk) ^ (rb & 7)) << 4));
            }
            #pragma unroll
            for (int fm = 0; fm < 4; ++fm)
                #pragma unroll
                for (int fn = 0; fn < 4; ++fn)
                    acc[fm][fn] = __builtin_amdgcn_mfma_f32_16x16x32_bf16(
                        af[fm], bg[fn], acc[fm][fn], 0, 0, 0);
        }

        #pragma unroll
        for (int fm = 0; fm < 4; ++fm) {
            #pragma unroll
            for (int j = 0; j < 4; ++j) {
                const int ql = wr + fm * 16 + lk * 4 + j;
                #pragma unroll
                for (int fn = 0; fn < 4; ++fn) {
                    const int c = cbase + wc + fn * 16 + lr;
                    float s = acc[fm][fn][j];
                    if (MODE == 0) {
                        int b = (int)((s + 1.0f) * (NBINS * 0.5f));
                        b = b < 0 ? 0 : (b > NBINS - 1 ? NBINS - 1 : b);
                        binsU8[(size_t)(qbase + ql) * MSAMPLE + c] = (unsigned char)b;
                    } else {
                        if (c < N && s >= thrv[fm][j]) {
                            int p = atomicAdd(&off_l[ql], 1);
                            if (p < BCAP)
                                buckets[((size_t)(qbase + ql) * NGRP + g) * BCAP + p] =
                                    (unsigned int)c;
                        }
                    }
                }
            }
        }
    }
    if (MODE == 1) {
        __syncthreads();
        for (int i = tid; i < 128; i += 256)
            cnt2[(qbase + i) * NGRP + g] = min(off_l[i], BCAP);
    }
}

// ---------------------------------------------------------------------------
// thresh with per-wave sub-histograms (removes inter-wave same-bin atomic serialization)
// ---------------------------------------------------------------------------
__global__ __launch_bounds__(256)
void thresh_kernel(const unsigned char* __restrict__ bins, float* __restrict__ thr)
{
    __shared__ int hS[4 * NBINS];
    __shared__ int hA[NBINS];
    __shared__ int hB[NBINS];
    __shared__ int best;
    const int q = blockIdx.x, tid = threadIdx.x;
    const int wv = tid >> 6;
    for (int i = tid; i < 4 * NBINS; i += 256) hS[i] = 0;
    if (tid == 0) best = 0;
    __syncthreads();
    const uint4* bp = reinterpret_cast<const uint4*>(bins + (size_t)q * MSAMPLE);
    int* hw = hS + wv * NBINS;
    for (int i = tid; i < MSAMPLE / 16; i += 256) {
        uint4 v = bp[i];
        unsigned xs[4] = {v.x, v.y, v.z, v.w};
        #pragma unroll
        for (int k = 0; k < 4; ++k) {
            unsigned x = xs[k];
            atomicAdd(&hw[x & 255], 1); x >>= 8;
            atomicAdd(&hw[x & 255], 1); x >>= 8;
            atomicAdd(&hw[x & 255], 1); x >>= 8;
            atomicAdd(&hw[x & 255], 1);
        }
    }
    __syncthreads();
    for (int i = tid; i < NBINS; i += 256)
        hA[i] = hS[i] + hS[NBINS + i] + hS[2 * NBINS + i] + hS[3 * NBINS + i];
    __syncthreads();
    int* src = hA; int* dst = hB;
    for (int off = 1; off < NBINS; off <<= 1) {
        for (int i = tid; i < NBINS; i += 256)
            dst[i] = src[i] + ((i + off < NBINS) ? src[i + off] : 0);
        __syncthreads();
        int* tmp = src; src = dst; dst = tmp;
    }
    for (int i = tid; i < NBINS; i += 256)
        if (src[i] >= TOPK) atomicMax(&best, i);
    __syncthreads();
    if (tid == 0)
        thr[q] = (float)(best - 1) * (2.0f / NBINS) - 1.0f;
}

// ---------------------------------------------------------------------------
// Finalize v2: compact -> exact fp32 rbf (4 lanes/candidate, 64 in flight) ->
// 1024-wide bitonic sort on u64 keys (rbf desc, idx asc) with all 4 waves ->
// weights, V/e gathers, outputs.
// ---------------------------------------------------------------------------
__global__ __launch_bounds__(256)
void finalize_kernel(const unsigned int* __restrict__ buckets, const int* __restrict__ cnt2,
                     const float* __restrict__ Qg, const float* __restrict__ Kg,
                     const float* __restrict__ V, const float* __restrict__ hIn,
                     const float* __restrict__ eIn,
                     float* __restrict__ out, int N)
{
    __shared__ float qv[DDIM];
    __shared__ int   cidxL[SORTN];                    // 4KB
    __shared__ unsigned long long sk[SORTN];          // 8KB sort keys
    __shared__ int   cnts[NGRP], offs[NGRP];
    __shared__ int   ntot;
    __shared__ float selV[TOPK];
    __shared__ int   selI[TOPK];
    __shared__ float wts[TOPK];
    const int q = blockIdx.x, tid = threadIdx.x;

    if (tid < DDIM) qv[tid] = Qg[(size_t)q * DDIM + tid];
    if (tid < NGRP) cnts[tid] = cnt2[q * NGRP + tid];
    for (int i = tid; i < SORTN; i += 256) sk[i] = 0ull;   // pad sorts last
    __syncthreads();
    if (tid < NGRP) {
        int c = cnts[tid];
        int x = c;
        #pragma unroll
        for (int o = 1; o < NGRP; o <<= 1) {
            int y = __shfl_up(x, o);
            if (tid >= o) x += y;
        }
        offs[tid] = x - c;
        if (tid == NGRP - 1) ntot = x;
    }
    __syncthreads();
    const int n = min(ntot, SORTN);
    for (int flat = tid; flat < NGRP * BCAP; flat += 256) {
        int gg = flat / BCAP, j = flat - gg * BCAP;
        if (j < cnts[gg]) {
            int dst = offs[gg] + j;
            if (dst < SORTN)
                cidxL[dst] = (int)buckets[((size_t)q * NGRP + gg) * BCAP + j];
        }
    }
    __syncthreads();
    // exact fp32 sims: 4 lanes per candidate, 64 candidates in flight
    const int sub = tid & 3, ci = tid >> 2;
    for (int base = 0; base < n; base += 64) {
        int i = base + ci;
        float s = 0.f;
        int c = 0;
        if (i < n) {
            c = cidxL[i];
            const float4* k4 = reinterpret_cast<const float4*>(Kg + (size_t)c * DDIM) + sub;
            const float4* q4 = reinterpret_cast<const float4*>(qv) + sub;
            #pragma unroll
            for (int d = 0; d < 8; ++d) {
                float4 kk = k4[d * 4];
                float4 qq = q4[d * 4];
                s = fmaf(qq.x, kk.x, s); s = fmaf(qq.y, kk.y, s);
                s = fmaf(qq.z, kk.z, s); s = fmaf(qq.w, kk.w, s);
            }
        }
        s += __shfl_xor(s, 1); s += __shfl_xor(s, 2);
        if (i < n && sub == 0) {
            float dist = 2.0f - 2.0f * s;              // reference op order
            float rbf = expf(dist * -2.0f);            // exp(-dist/(2*0.25))
            sk[i] = ((unsigned long long)__float_as_uint(rbf) << 32)
                    | (unsigned)(~(unsigned)c);        // rbf desc, then idx asc
        }
    }
    __syncthreads();
    // bitonic sort, descending, 1024 elems, all 256 threads
    for (int k = 2; k <= SORTN; k <<= 1) {
        for (int j = k >> 1; j > 0; j >>= 1) {
            for (int t = tid; t < SORTN; t += 256) {
                int x = t ^ j;
                if (x > t) {
                    unsigned long long a = sk[t], b = sk[x];
                    bool sw = ((t & k) == 0) ? (a < b) : (a > b);
                    if (sw) { sk[t] = b; sk[x] = a; }
                }
            }
            __syncthreads();
        }
    }
    if (tid < TOPK) {
        unsigned long long kk = sk[tid];
        float rbf = __uint_as_float((unsigned)(kk >> 32));
        int   idx = (int)(~(unsigned)kk);
        selV[tid] = rbf; selI[tid] = idx;
        float lw = logf(rbf + 1e-8f) + logf(hIn[idx] + 1e-8f);
        float mx = lw;
        #pragma unroll
        for (int o = 16; o > 0; o >>= 1) mx = fmaxf(mx, __shfl_xor(mx, o));
        float ex = expf(lw - mx);
        float sm = ex;
        #pragma unroll
        for (int o = 16; o > 0; o >>= 1) sm += __shfl_xor(sm, o);
        wts[tid] = ex / sm;
    }
    __syncthreads();
    {
        float acc = 0.f;
        const int v = tid;
        #pragma unroll
        for (int k = 0; k < TOPK; ++k)
            acc = fmaf(wts[k], V[(size_t)selI[k] * 256 + v], acc);
        out[(size_t)q * 256 + v] = acc;
    }
    const int offE = NQTOT * 256;
    const int offW = offE + NQTOT * 4;
    const int offI = offW + NQTOT * TOPK;
    if (tid < 4) {
        float acc = 0.f;
        #pragma unroll
        for (int k = 0; k < TOPK; ++k)
            acc = fmaf(wts[k], eIn[(size_t)selI[k] * 4 + tid], acc);
        out[offE + q * 4 + tid] = acc;
    }
    if (tid < TOPK) {
        out[offW + q * TOPK + tid] = wts[tid];
        out[offI + q * TOPK + tid] = (float)selI[tid];
    }
}

// ---------------------------------------------------------------------------
extern "C" void kernel_launch(void* const* d_in, const int* in_sizes, int n_in,
                              void* d_out, int out_size, void* d_ws, size_t ws_size,
                              hipStream_t stream)
{
    (void)n_in; (void)out_size; (void)ws_size;
    const float* Qg = (const float*)d_in[0];
    const float* Kg = (const float*)d_in[1];
    const float* Vg = (const float*)d_in[2];
    const float* hg = (const float*)d_in[3];
    const float* eg = (const float*)d_in[4];
    const int N = in_sizes[1] / DDIM;          // 100000

    char* w = (char*)d_ws;
    unsigned short* Kbf = (unsigned short*)w;  w += (size_t)N * DDIM * 2;      // 25.6MB
    unsigned short* Qbf = (unsigned short*)w;  w += (size_t)NQTOT * DDIM * 2;  // 256KB
    float* thr = (float*)w;                    w += NQTOT * 4;                 // 4KB
    int*   cnt2 = (int*)w;                     w += (size_t)NQTOT * NGRP * 4;  // 256KB
    unsigned char* binsU8 = (unsigned char*)w;                                 // 12.58MB
    unsigned int*  buckets = (unsigned int*)w; // aliases binsU8 (sequential lifetimes)

    hipMemsetAsync(cnt2, 0, (size_t)NQTOT * NGRP * 4, stream);

    dim3 blk(256);
    convert_kernel<<<dim3(2048), blk, 0, stream>>>(
        Qg, Kg, Qbf, Kbf, NQTOT * DDIM / 8, N * DDIM / 8);
    gemm_pass<0><<<dim3(MSAMPLE / 128, NQTOT / 128), blk, 0, stream>>>(
        Qbf, Kbf, N, binsU8, nullptr, nullptr, nullptr);
    thresh_kernel<<<dim3(NQTOT), blk, 0, stream>>>(binsU8, thr);
    gemm_pass<1><<<dim3(NGRP, NQTOT / 128), blk, 0, stream>>>(
        Qbf, Kbf, N, nullptr, thr, cnt2, buckets);
    finalize_kernel<<<dim3(NQTOT), blk, 0, stream>>>(
        buckets, cnt2, Qg, Kg, Vg, hg, eg, (float*)d_out, N);
}

// Round 6
// 188.654 us; speedup vs baseline: 7.2828x; 1.0860x over previous
//
#include <hip/hip_runtime.h>
#include <math.h>

// MemoryCenters: sim = q·K^T (1024x100000, D=128), top-32 by rbf=exp(-2*dist_sq),
// softmax(log(rbf+eps)+log(h+eps)), r_V = w·V_sel, r_E = w·e_sel.
//
// Round 6 = Round 5 with gemm_pass restructured for latency hiding:
//   - A(Q)-tile in REGISTERS (16 short8/lane, loaded once per block)
//   - B tile double-buffered, staged via global_load_lds (width 16) with
//     pre-swizzled global source + linear LDS dest + swizzled read (XOR involution)
//   - 2-phase pipeline: issue next tile's staging BEFORE current tile's compute;
//     single __syncthreads per tile (vmcnt drain hidden under ~1500cy of MFMA).
// convert/thresh/finalize identical to passing R5.
// ws: 25.6MB Kbf + 256KB Qbf + 4KB thr + 256KB cnt2 + 12.58MB (binsU8|buckets).

#define DDIM    128
#define MSAMPLE 12288
#define NBINS   256
#define TOPK    32
#define NQTOT   1024
#define NGRP    64
#define BCAP    48
#define EPSM    0.012f
#define SORTN   1024

typedef __attribute__((ext_vector_type(8))) short short8;   // 8 bf16 = 4 VGPRs
typedef __attribute__((ext_vector_type(4))) float f32x4;    // mfma C/D frag

__device__ inline unsigned short f2bf(float f) {
    unsigned u = __builtin_bit_cast(unsigned, f);
    return (unsigned short)((u + 0x7FFFu + ((u >> 16) & 1u)) >> 16);
}

// ---------------------------------------------------------------------------
__global__ __launch_bounds__(256)
void convert_kernel(const float* __restrict__ Qg, const float* __restrict__ Kg,
                    unsigned short* __restrict__ Qbf, unsigned short* __restrict__ Kbf,
                    int nq8, int nk8)
{
    int total = nq8 + nk8;
    for (int i = blockIdx.x * 256 + threadIdx.x; i < total; i += gridDim.x * 256) {
        const float* s; unsigned short* d; int j;
        if (i < nq8) { s = Qg; d = Qbf; j = i; }
        else         { s = Kg; d = Kbf; j = i - nq8; }
        float4 a = *reinterpret_cast<const float4*>(s + (size_t)j * 8);
        float4 b = *reinterpret_cast<const float4*>(s + (size_t)j * 8 + 4);
        short8 o;
        o[0] = (short)f2bf(a.x); o[1] = (short)f2bf(a.y);
        o[2] = (short)f2bf(a.z); o[3] = (short)f2bf(a.w);
        o[4] = (short)f2bf(b.x); o[5] = (short)f2bf(b.y);
        o[6] = (short)f2bf(b.z); o[7] = (short)f2bf(b.w);
        *reinterpret_cast<short8*>(d + (size_t)j * 8) = o;
    }
}

// ---------------------------------------------------------------------------
// bf16 MFMA GEMM, 128x128 tile, A in registers, B double-buffered via
// global_load_lds (pre-swizzled source, linear LDS dest, swizzled read).
// MODE 0: write u8 bins for sample sims. MODE 1: bucket-append survivors.
// ---------------------------------------------------------------------------
template<int MODE>
__global__ __launch_bounds__(256)
void gemm_pass(const unsigned short* __restrict__ Qb, const unsigned short* __restrict__ Kb,
               int N, unsigned char* __restrict__ binsU8,
               const float* __restrict__ thr,
               int* __restrict__ cnt2, unsigned int* __restrict__ buckets)
{
    __shared__ __align__(16) unsigned char Bs[2][128 * 256];  // 2 x 32KB
    __shared__ int off_l[128];
    const int tid   = threadIdx.x;
    const int lane  = tid & 63;
    const int w     = tid >> 6;
    const int wr    = (w >> 1) * 64;
    const int wc    = (w & 1) * 64;
    const int lr    = lane & 15;
    const int lk    = lane >> 4;
    const int g     = blockIdx.x;
    const int qbase = blockIdx.y * 128;

    int t0, tcnt;
    if (MODE == 0) { t0 = g; tcnt = 1; }
    else { t0 = g * 12 + min(g, 14); tcnt = 12 + (g < 14 ? 1 : 0); }

    if (MODE == 1)
        for (int i = tid; i < 128; i += 256) off_l[i] = 0;

// stage tile's B into Bs[buf]: linear LDS dest (wave-uniform base + lane*16),
// global source pre-swizzled by the XOR involution, so swizzled reads see
// global chunk (ks*4+lk) at row rb.  16B-wide global_load_lds (direct to LDS).
#define STAGE(buf, tile) do {                                                  \
    const int cbase_ = (tile) * 128;                                           \
    _Pragma("unroll")                                                          \
    for (int it = 0; it < 8; ++it) {                                           \
        int flat = it * 256 + tid;                                             \
        int r_ = flat >> 4, cc_ = flat & 15;                                   \
        int row_ = cbase_ + r_;                                                \
        if (MODE == 1 && row_ >= N) row_ = N - 1;  /* epilogue c<N discards */ \
        const unsigned short* src_ = Kb + (size_t)row_ * DDIM                  \
                                        + ((cc_ ^ (r_ & 7)) * 8);              \
        unsigned char* dst_ = &Bs[buf][(size_t)(it * 256 + (tid & ~63)) * 16]; \
        __builtin_amdgcn_global_load_lds(                                      \
            (const __attribute__((address_space(1))) unsigned int*)src_,       \
            (__attribute__((address_space(3))) unsigned int*)dst_, 16, 0, 0);  \
    }                                                                          \
} while (0)

    // ---- A fragments in registers: af[fm][ks], 16 x short8 = 64 VGPR ----
    short8 af[4][4];
    #pragma unroll
    for (int fm = 0; fm < 4; ++fm)
        #pragma unroll
        for (int ks = 0; ks < 4; ++ks)
            af[fm][ks] = *reinterpret_cast<const short8*>(
                Qb + (size_t)(qbase + wr + fm * 16 + lr) * DDIM + (ks * 4 + lk) * 8);

    float thrv[4][4];
    if (MODE == 1) {
        #pragma unroll
        for (int fm = 0; fm < 4; ++fm)
            #pragma unroll
            for (int j = 0; j < 4; ++j)
                thrv[fm][j] = thr[qbase + wr + fm * 16 + lk * 4 + j] - EPSM;
    }

    // prologue: stage tile 0 into buf 0
    STAGE(0, t0);
    __syncthreads();            // vmcnt(0) drain + barrier
    int cur = 0;

    for (int t = 0; t < tcnt; ++t) {
        if (t + 1 < tcnt) STAGE(cur ^ 1, t0 + t + 1);   // in flight under compute

        const int cbase = (t0 + t) * 128;
        const unsigned char* bsc = Bs[cur];

        const f32x4 z = {0.f, 0.f, 0.f, 0.f};
        f32x4 acc[4][4];
        #pragma unroll
        for (int a = 0; a < 4; ++a)
            #pragma unroll
            for (int b = 0; b < 4; ++b) acc[a][b] = z;

        #pragma unroll
        for (int ks = 0; ks < 4; ++ks) {
            short8 bg[4];
            #pragma unroll
            for (int fn = 0; fn < 4; ++fn) {
                int rb = wc + fn * 16 + lr;
                bg[fn] = *reinterpret_cast<const short8*>(
                    bsc + rb * 256 + (((ks * 4 + lk) ^ (rb & 7)) << 4));
            }
            #pragma unroll
            for (int fm = 0; fm < 4; ++fm)
                #pragma unroll
                for (int fn = 0; fn < 4; ++fn)
                    acc[fm][fn] = __builtin_amdgcn_mfma_f32_16x16x32_bf16(
                        af[fm][ks], bg[fn], acc[fm][fn], 0, 0, 0);
        }

        // epilogue — C/D map: col = lane&15, row = (lane>>4)*4 + reg [m89/m91]
        #pragma unroll
        for (int fm = 0; fm < 4; ++fm) {
            #pragma unroll
            for (int j = 0; j < 4; ++j) {
                const int ql = wr + fm * 16 + lk * 4 + j;
                #pragma unroll
                for (int fn = 0; fn < 4; ++fn) {
                    const int c = cbase + wc + fn * 16 + lr;
                    float s = acc[fm][fn][j];
                    if (MODE == 0) {
                        int b = (int)((s + 1.0f) * (NBINS * 0.5f));
                        b = b < 0 ? 0 : (b > NBINS - 1 ? NBINS - 1 : b);
                        binsU8[(size_t)(qbase + ql) * MSAMPLE + c] = (unsigned char)b;
                    } else {
                        if (c < N && s >= thrv[fm][j]) {
                            int p = atomicAdd(&off_l[ql], 1);   // LDS-local only
                            if (p < BCAP)
                                buckets[((size_t)(qbase + ql) * NGRP + g) * BCAP + p] =
                                    (unsigned int)c;
                        }
                    }
                }
            }
        }
        __syncthreads();        // staging of t+1 drained; readers of cur done
        cur ^= 1;
    }
#undef STAGE

    if (MODE == 1) {
        for (int i = tid; i < 128; i += 256)
            cnt2[(qbase + i) * NGRP + g] = min(off_l[i], BCAP);
    }
}

// ---------------------------------------------------------------------------
// thresh with per-wave sub-histograms
// ---------------------------------------------------------------------------
__global__ __launch_bounds__(256)
void thresh_kernel(const unsigned char* __restrict__ bins, float* __restrict__ thr)
{
    __shared__ int hS[4 * NBINS];
    __shared__ int hA[NBINS];
    __shared__ int hB[NBINS];
    __shared__ int best;
    const int q = blockIdx.x, tid = threadIdx.x;
    const int wv = tid >> 6;
    for (int i = tid; i < 4 * NBINS; i += 256) hS[i] = 0;
    if (tid == 0) best = 0;
    __syncthreads();
    const uint4* bp = reinterpret_cast<const uint4*>(bins + (size_t)q * MSAMPLE);
    int* hw = hS + wv * NBINS;
    for (int i = tid; i < MSAMPLE / 16; i += 256) {
        uint4 v = bp[i];
        unsigned xs[4] = {v.x, v.y, v.z, v.w};
        #pragma unroll
        for (int k = 0; k < 4; ++k) {
            unsigned x = xs[k];
            atomicAdd(&hw[x & 255], 1); x >>= 8;
            atomicAdd(&hw[x & 255], 1); x >>= 8;
            atomicAdd(&hw[x & 255], 1); x >>= 8;
            atomicAdd(&hw[x & 255], 1);
        }
    }
    __syncthreads();
    for (int i = tid; i < NBINS; i += 256)
        hA[i] = hS[i] + hS[NBINS + i] + hS[2 * NBINS + i] + hS[3 * NBINS + i];
    __syncthreads();
    int* src = hA; int* dst = hB;
    for (int off = 1; off < NBINS; off <<= 1) {
        for (int i = tid; i < NBINS; i += 256)
            dst[i] = src[i] + ((i + off < NBINS) ? src[i + off] : 0);
        __syncthreads();
        int* tmp = src; src = dst; dst = tmp;
    }
    for (int i = tid; i < NBINS; i += 256)
        if (src[i] >= TOPK) atomicMax(&best, i);
    __syncthreads();
    if (tid == 0)
        thr[q] = (float)(best - 1) * (2.0f / NBINS) - 1.0f;
}

// ---------------------------------------------------------------------------
// Finalize: compact -> exact fp32 rbf -> 1024-wide bitonic sort on u64 keys
// (rbf desc, idx asc = jax.lax.top_k) -> weights, V/e gathers, outputs.
// ---------------------------------------------------------------------------
__global__ __launch_bounds__(256)
void finalize_kernel(const unsigned int* __restrict__ buckets, const int* __restrict__ cnt2,
                     const float* __restrict__ Qg, const float* __restrict__ Kg,
                     const float* __restrict__ V, const float* __restrict__ hIn,
                     const float* __restrict__ eIn,
                     float* __restrict__ out, int N)
{
    __shared__ float qv[DDIM];
    __shared__ int   cidxL[SORTN];
    __shared__ unsigned long long sk[SORTN];
    __shared__ int   cnts[NGRP], offs[NGRP];
    __shared__ int   ntot;
    __shared__ float selV[TOPK];
    __shared__ int   selI[TOPK];
    __shared__ float wts[TOPK];
    const int q = blockIdx.x, tid = threadIdx.x;

    if (tid < DDIM) qv[tid] = Qg[(size_t)q * DDIM + tid];
    if (tid < NGRP) cnts[tid] = cnt2[q * NGRP + tid];
    for (int i = tid; i < SORTN; i += 256) sk[i] = 0ull;   // pad sorts last
    __syncthreads();
    if (tid < NGRP) {
        int c = cnts[tid];
        int x = c;
        #pragma unroll
        for (int o = 1; o < NGRP; o <<= 1) {
            int y = __shfl_up(x, o);
            if (tid >= o) x += y;
        }
        offs[tid] = x - c;
        if (tid == NGRP - 1) ntot = x;
    }
    __syncthreads();
    const int n = min(ntot, SORTN);
    for (int flat = tid; flat < NGRP * BCAP; flat += 256) {
        int gg = flat / BCAP, j = flat - gg * BCAP;
        if (j < cnts[gg]) {
            int dst = offs[gg] + j;
            if (dst < SORTN)
                cidxL[dst] = (int)buckets[((size_t)q * NGRP + gg) * BCAP + j];
        }
    }
    __syncthreads();
    // exact fp32 sims: 4 lanes per candidate, 64 candidates in flight
    const int sub = tid & 3, ci = tid >> 2;
    for (int base = 0; base < n; base += 64) {
        int i = base + ci;
        float s = 0.f;
        int c = 0;
        if (i < n) {
            c = cidxL[i];
            const float4* k4 = reinterpret_cast<const float4*>(Kg + (size_t)c * DDIM) + sub;
            const float4* q4 = reinterpret_cast<const float4*>(qv) + sub;
            #pragma unroll
            for (int d = 0; d < 8; ++d) {
                float4 kk = k4[d * 4];
                float4 qq = q4[d * 4];
                s = fmaf(qq.x, kk.x, s); s = fmaf(qq.y, kk.y, s);
                s = fmaf(qq.z, kk.z, s); s = fmaf(qq.w, kk.w, s);
            }
        }
        s += __shfl_xor(s, 1); s += __shfl_xor(s, 2);
        if (i < n && sub == 0) {
            float dist = 2.0f - 2.0f * s;              // reference op order
            float rbf = expf(dist * -2.0f);            // exp(-dist/(2*0.25))
            sk[i] = ((unsigned long long)__float_as_uint(rbf) << 32)
                    | (unsigned)(~(unsigned)c);        // rbf desc, then idx asc
        }
    }
    __syncthreads();
    // bitonic sort, descending, 1024 elems, all 256 threads
    for (int k = 2; k <= SORTN; k <<= 1) {
        for (int j = k >> 1; j > 0; j >>= 1) {
            for (int t = tid; t < SORTN; t += 256) {
                int x = t ^ j;
                if (x > t) {
                    unsigned long long a = sk[t], b = sk[x];
                    bool sw = ((t & k) == 0) ? (a < b) : (a > b);
                    if (sw) { sk[t] = b; sk[x] = a; }
                }
            }
            __syncthreads();
        }
    }
    if (tid < TOPK) {
        unsigned long long kk = sk[tid];
        float rbf = __uint_as_float((unsigned)(kk >> 32));
        int   idx = (int)(~(unsigned)kk);
        selV[tid] = rbf; selI[tid] = idx;
        float lw = logf(rbf + 1e-8f) + logf(hIn[idx] + 1e-8f);
        float mx = lw;
        #pragma unroll
        for (int o = 16; o > 0; o >>= 1) mx = fmaxf(mx, __shfl_xor(mx, o));
        float ex = expf(lw - mx);
        float sm = ex;
        #pragma unroll
        for (int o = 16; o > 0; o >>= 1) sm += __shfl_xor(sm, o);
        wts[tid] = ex / sm;
    }
    __syncthreads();
    {
        float acc = 0.f;
        const int v = tid;
        #pragma unroll
        for (int k = 0; k < TOPK; ++k)
            acc = fmaf(wts[k], V[(size_t)selI[k] * 256 + v], acc);
        out[(size_t)q * 256 + v] = acc;
    }
    const int offE = NQTOT * 256;
    const int offW = offE + NQTOT * 4;
    const int offI = offW + NQTOT * TOPK;
    if (tid < 4) {
        float acc = 0.f;
        #pragma unroll
        for (int k = 0; k < TOPK; ++k)
            acc = fmaf(wts[k], eIn[(size_t)selI[k] * 4 + tid], acc);
        out[offE + q * 4 + tid] = acc;
    }
    if (tid < TOPK) {
        out[offW + q * TOPK + tid] = wts[tid];
        out[offI + q * TOPK + tid] = (float)selI[tid];
    }
}

// ---------------------------------------------------------------------------
extern "C" void kernel_launch(void* const* d_in, const int* in_sizes, int n_in,
                              void* d_out, int out_size, void* d_ws, size_t ws_size,
                              hipStream_t stream)
{
    (void)n_in; (void)out_size; (void)ws_size;
    const float* Qg = (const float*)d_in[0];
    const float* Kg = (const float*)d_in[1];
    const float* Vg = (const float*)d_in[2];
    const float* hg = (const float*)d_in[3];
    const float* eg = (const float*)d_in[4];
    const int N = in_sizes[1] / DDIM;          // 100000

    char* w = (char*)d_ws;
    unsigned short* Kbf = (unsigned short*)w;  w += (size_t)N * DDIM * 2;      // 25.6MB
    unsigned short* Qbf = (unsigned short*)w;  w += (size_t)NQTOT * DDIM * 2;  // 256KB
    float* thr = (float*)w;                    w += NQTOT * 4;                 // 4KB
    int*   cnt2 = (int*)w;                     w += (size_t)NQTOT * NGRP * 4;  // 256KB
    unsigned char* binsU8 = (unsigned char*)w;                                 // 12.58MB
    unsigned int*  buckets = (unsigned int*)w; // aliases binsU8 (sequential lifetimes)

    hipMemsetAsync(cnt2, 0, (size_t)NQTOT * NGRP * 4, stream);

    dim3 blk(256);
    convert_kernel<<<dim3(2048), blk, 0, stream>>>(
        Qg, Kg, Qbf, Kbf, NQTOT * DDIM / 8, N * DDIM / 8);
    gemm_pass<0><<<dim3(MSAMPLE / 128, NQTOT / 128), blk, 0, stream>>>(
        Qbf, Kbf, N, binsU8, nullptr, nullptr, nullptr);
    thresh_kernel<<<dim3(NQTOT), blk, 0, stream>>>(binsU8, thr);
    gemm_pass<1><<<dim3(NGRP, NQTOT / 128), blk, 0, stream>>>(
        Qbf, Kbf, N, nullptr, thr, cnt2, buckets);
    finalize_kernel<<<dim3(NQTOT), blk, 0, stream>>>(
        buckets, cnt2, Qg, Kg, Vg, hg, eg, (float*)d_out, N);
}

// Round 7
// 160.962 us; speedup vs baseline: 8.5357x; 1.1720x over previous
//
#include <hip/hip_runtime.h>
#include <math.h>

// MemoryCenters: sim = q·K^T (1024x100000, D=128), top-32 by rbf=exp(-2*dist_sq),
// softmax(log(rbf+eps)+log(h+eps)), r_V = w·V_sel, r_E = w·e_sel.
//
// Round 7 = Round 6 with finalize made cheap on gather traffic:
//   - pass2 packs survivors as u32 key = quant15(sim)<<17 | (~idx & 0x1FFFF)
//   - finalize: bitonic-sort 1024 u32 approx keys (desc); exact fp32 recompute
//     ONLY for head slots within 200 quanta (0.0122) of the 32nd approx key
//     (margin >= 2*EA + quantization; EA<=0.004 bf16-dot error) -> ~70 rows
//     instead of ~680 -> K-gather 356MB -> ~37MB; then 256-wide u64 bitonic
//     on (exact rbf, ~idx) = jax.lax.top_k order; weights/gathers unchanged.
// convert/gemm staging/thresh identical to passing R6.
// ws: 25.6MB Kbf + 256KB Qbf + 4KB thr + 256KB cnt2 + 12.58MB (binsU8|buckets).

#define DDIM    128
#define MSAMPLE 12288
#define NBINS   256
#define TOPK    32
#define NQTOT   1024
#define NGRP    64
#define BCAP    48
#define EPSM    0.012f
#define SORTN   1024
#define FINEN   256
#define QSH     17
#define QMASK   0x1FFFFu
#define QMARGIN 200u      // 200/16384 = 0.0122 >= 2*EA(0.004) + 2 quanta

typedef __attribute__((ext_vector_type(8))) short short8;   // 8 bf16 = 4 VGPRs
typedef __attribute__((ext_vector_type(4))) float f32x4;    // mfma C/D frag

__device__ inline unsigned short f2bf(float f) {
    unsigned u = __builtin_bit_cast(unsigned, f);
    return (unsigned short)((u + 0x7FFFu + ((u >> 16) & 1u)) >> 16);
}

// ---------------------------------------------------------------------------
__global__ __launch_bounds__(256)
void convert_kernel(const float* __restrict__ Qg, const float* __restrict__ Kg,
                    unsigned short* __restrict__ Qbf, unsigned short* __restrict__ Kbf,
                    int nq8, int nk8)
{
    int total = nq8 + nk8;
    for (int i = blockIdx.x * 256 + threadIdx.x; i < total; i += gridDim.x * 256) {
        const float* s; unsigned short* d; int j;
        if (i < nq8) { s = Qg; d = Qbf; j = i; }
        else         { s = Kg; d = Kbf; j = i - nq8; }
        float4 a = *reinterpret_cast<const float4*>(s + (size_t)j * 8);
        float4 b = *reinterpret_cast<const float4*>(s + (size_t)j * 8 + 4);
        short8 o;
        o[0] = (short)f2bf(a.x); o[1] = (short)f2bf(a.y);
        o[2] = (short)f2bf(a.z); o[3] = (short)f2bf(a.w);
        o[4] = (short)f2bf(b.x); o[5] = (short)f2bf(b.y);
        o[6] = (short)f2bf(b.z); o[7] = (short)f2bf(b.w);
        *reinterpret_cast<short8*>(d + (size_t)j * 8) = o;
    }
}

// ---------------------------------------------------------------------------
// bf16 MFMA GEMM, 128x128 tile, A in registers, B double-buffered via
// global_load_lds (pre-swizzled source, linear LDS dest, swizzled read).
// MODE 0: write u8 bins for sample sims. MODE 1: bucket-append packed keys.
// ---------------------------------------------------------------------------
template<int MODE>
__global__ __launch_bounds__(256)
void gemm_pass(const unsigned short* __restrict__ Qb, const unsigned short* __restrict__ Kb,
               int N, unsigned char* __restrict__ binsU8,
               const float* __restrict__ thr,
               int* __restrict__ cnt2, unsigned int* __restrict__ buckets)
{
    __shared__ __align__(16) unsigned char Bs[2][128 * 256];  // 2 x 32KB
    __shared__ int off_l[128];
    const int tid   = threadIdx.x;
    const int lane  = tid & 63;
    const int w     = tid >> 6;
    const int wr    = (w >> 1) * 64;
    const int wc    = (w & 1) * 64;
    const int lr    = lane & 15;
    const int lk    = lane >> 4;
    const int g     = blockIdx.x;
    const int qbase = blockIdx.y * 128;

    int t0, tcnt;
    if (MODE == 0) { t0 = g; tcnt = 1; }
    else { t0 = g * 12 + min(g, 14); tcnt = 12 + (g < 14 ? 1 : 0); }

    if (MODE == 1)
        for (int i = tid; i < 128; i += 256) off_l[i] = 0;

#define STAGE(buf, tile) do {                                                  \
    const int cbase_ = (tile) * 128;                                           \
    _Pragma("unroll")                                                          \
    for (int it = 0; it < 8; ++it) {                                           \
        int flat = it * 256 + tid;                                             \
        int r_ = flat >> 4, cc_ = flat & 15;                                   \
        int row_ = cbase_ + r_;                                                \
        if (MODE == 1 && row_ >= N) row_ = N - 1;  /* epilogue c<N discards */ \
        const unsigned short* src_ = Kb + (size_t)row_ * DDIM                  \
                                        + ((cc_ ^ (r_ & 7)) * 8);              \
        unsigned char* dst_ = &Bs[buf][(size_t)(it * 256 + (tid & ~63)) * 16]; \
        __builtin_amdgcn_global_load_lds(                                      \
            (const __attribute__((address_space(1))) unsigned int*)src_,       \
            (__attribute__((address_space(3))) unsigned int*)dst_, 16, 0, 0);  \
    }                                                                          \
} while (0)

    // ---- A fragments in registers ----
    short8 af[4][4];
    #pragma unroll
    for (int fm = 0; fm < 4; ++fm)
        #pragma unroll
        for (int ks = 0; ks < 4; ++ks)
            af[fm][ks] = *reinterpret_cast<const short8*>(
                Qb + (size_t)(qbase + wr + fm * 16 + lr) * DDIM + (ks * 4 + lk) * 8);

    float thrv[4][4];
    if (MODE == 1) {
        #pragma unroll
        for (int fm = 0; fm < 4; ++fm)
            #pragma unroll
            for (int j = 0; j < 4; ++j)
                thrv[fm][j] = thr[qbase + wr + fm * 16 + lk * 4 + j] - EPSM;
    }

    STAGE(0, t0);
    __syncthreads();
    int cur = 0;

    for (int t = 0; t < tcnt; ++t) {
        if (t + 1 < tcnt) STAGE(cur ^ 1, t0 + t + 1);

        const int cbase = (t0 + t) * 128;
        const unsigned char* bsc = Bs[cur];

        const f32x4 z = {0.f, 0.f, 0.f, 0.f};
        f32x4 acc[4][4];
        #pragma unroll
        for (int a = 0; a < 4; ++a)
            #pragma unroll
            for (int b = 0; b < 4; ++b) acc[a][b] = z;

        #pragma unroll
        for (int ks = 0; ks < 4; ++ks) {
            short8 bg[4];
            #pragma unroll
            for (int fn = 0; fn < 4; ++fn) {
                int rb = wc + fn * 16 + lr;
                bg[fn] = *reinterpret_cast<const short8*>(
                    bsc + rb * 256 + (((ks * 4 + lk) ^ (rb & 7)) << 4));
            }
            #pragma unroll
            for (int fm = 0; fm < 4; ++fm)
                #pragma unroll
                for (int fn = 0; fn < 4; ++fn)
                    acc[fm][fn] = __builtin_amdgcn_mfma_f32_16x16x32_bf16(
                        af[fm][ks], bg[fn], acc[fm][fn], 0, 0, 0);
        }

        // epilogue — C/D map: col = lane&15, row = (lane>>4)*4 + reg [m89/m91]
        #pragma unroll
        for (int fm = 0; fm < 4; ++fm) {
            #pragma unroll
            for (int j = 0; j < 4; ++j) {
                const int ql = wr + fm * 16 + lk * 4 + j;
                #pragma unroll
                for (int fn = 0; fn < 4; ++fn) {
                    const int c = cbase + wc + fn * 16 + lr;
                    float s = acc[fm][fn][j];
                    if (MODE == 0) {
                        int b = (int)((s + 1.0f) * (NBINS * 0.5f));
                        b = b < 0 ? 0 : (b > NBINS - 1 ? NBINS - 1 : b);
                        binsU8[(size_t)(qbase + ql) * MSAMPLE + c] = (unsigned char)b;
                    } else {
                        if (c < N && s >= thrv[fm][j]) {
                            int qs = (int)((s + 1.0f) * 16384.0f);
                            qs = qs < 0 ? 0 : (qs > 32767 ? 32767 : qs);
                            unsigned key = ((unsigned)qs << QSH)
                                         | (~(unsigned)c & QMASK);
                            int p = atomicAdd(&off_l[ql], 1);   // LDS-local only
                            if (p < BCAP)
                                buckets[((size_t)(qbase + ql) * NGRP + g) * BCAP + p] = key;
                        }
                    }
                }
            }
        }
        __syncthreads();
        cur ^= 1;
    }
#undef STAGE

    if (MODE == 1) {
        for (int i = tid; i < 128; i += 256)
            cnt2[(qbase + i) * NGRP + g] = min(off_l[i], BCAP);
    }
}

// ---------------------------------------------------------------------------
// thresh with per-wave sub-histograms
// ---------------------------------------------------------------------------
__global__ __launch_bounds__(256)
void thresh_kernel(const unsigned char* __restrict__ bins, float* __restrict__ thr)
{
    __shared__ int hS[4 * NBINS];
    __shared__ int hA[NBINS];
    __shared__ int hB[NBINS];
    __shared__ int best;
    const int q = blockIdx.x, tid = threadIdx.x;
    const int wv = tid >> 6;
    for (int i = tid; i < 4 * NBINS; i += 256) hS[i] = 0;
    if (tid == 0) best = 0;
    __syncthreads();
    const uint4* bp = reinterpret_cast<const uint4*>(bins + (size_t)q * MSAMPLE);
    int* hw = hS + wv * NBINS;
    for (int i = tid; i < MSAMPLE / 16; i += 256) {
        uint4 v = bp[i];
        unsigned xs[4] = {v.x, v.y, v.z, v.w};
        #pragma unroll
        for (int k = 0; k < 4; ++k) {
            unsigned x = xs[k];
            atomicAdd(&hw[x & 255], 1); x >>= 8;
            atomicAdd(&hw[x & 255], 1); x >>= 8;
            atomicAdd(&hw[x & 255], 1); x >>= 8;
            atomicAdd(&hw[x & 255], 1);
        }
    }
    __syncthreads();
    for (int i = tid; i < NBINS; i += 256)
        hA[i] = hS[i] + hS[NBINS + i] + hS[2 * NBINS + i] + hS[3 * NBINS + i];
    __syncthreads();
    int* src = hA; int* dst = hB;
    for (int off = 1; off < NBINS; off <<= 1) {
        for (int i = tid; i < NBINS; i += 256)
            dst[i] = src[i] + ((i + off < NBINS) ? src[i + off] : 0);
        __syncthreads();
        int* tmp = src; src = dst; dst = tmp;
    }
    for (int i = tid; i < NBINS; i += 256)
        if (src[i] >= TOPK) atomicMax(&best, i);
    __syncthreads();
    if (tid == 0)
        thr[q] = (float)(best - 1) * (2.0f / NBINS) - 1.0f;
}

// ---------------------------------------------------------------------------
// Finalize v3: compact packed keys -> 1024-wide u32 bitonic (approx desc) ->
// exact fp32 rbf ONLY for head slots within QMARGIN of 32nd approx key ->
// 256-wide u64 bitonic (rbf desc, idx asc = jax.lax.top_k) -> weights, gathers.
// ---------------------------------------------------------------------------
__global__ __launch_bounds__(256)
void finalize_kernel(const unsigned int* __restrict__ buckets, const int* __restrict__ cnt2,
                     const float* __restrict__ Qg, const float* __restrict__ Kg,
                     const float* __restrict__ V, const float* __restrict__ hIn,
                     const float* __restrict__ eIn,
                     float* __restrict__ out, int N)
{
    __shared__ float qv[DDIM];
    __shared__ unsigned sk[SORTN];                 // 4KB packed approx keys
    __shared__ unsigned long long sk64[FINEN];     // 2KB exact keys
    __shared__ int cnts[NGRP], offs[NGRP];
    __shared__ int ntot;
    __shared__ float selV[TOPK];
    __shared__ int   selI[TOPK];
    __shared__ float wts[TOPK];
    const int q = blockIdx.x, tid = threadIdx.x;

    if (tid < DDIM) qv[tid] = Qg[(size_t)q * DDIM + tid];
    if (tid < NGRP) cnts[tid] = cnt2[q * NGRP + tid];
    for (int i = tid; i < SORTN; i += 256) sk[i] = 0u;     // pad sorts last
    if (tid < FINEN) sk64[tid] = 0ull;
    __syncthreads();
    if (tid < NGRP) {
        int c = cnts[tid];
        int x = c;
        #pragma unroll
        for (int o = 1; o < NGRP; o <<= 1) {
            int y = __shfl_up(x, o);
            if (tid >= o) x += y;
        }
        offs[tid] = x - c;
        if (tid == NGRP - 1) ntot = x;
    }
    __syncthreads();
    for (int flat = tid; flat < NGRP * BCAP; flat += 256) {
        int gg = flat / BCAP, j = flat - gg * BCAP;
        if (j < cnts[gg]) {
            int dst = offs[gg] + j;
            if (dst < SORTN)
                sk[dst] = buckets[((size_t)q * NGRP + gg) * BCAP + j];
        }
    }
    __syncthreads();
    // bitonic sort u32 desc, 1024 elems, 256 threads
    for (int k = 2; k <= SORTN; k <<= 1) {
        for (int j = k >> 1; j > 0; j >>= 1) {
            for (int t = tid; t < SORTN; t += 256) {
                int x = t ^ j;
                if (x > t) {
                    unsigned a = sk[t], b = sk[x];
                    bool sw = ((t & k) == 0) ? (a < b) : (a > b);
                    if (sw) { sk[t] = b; sk[x] = a; }
                }
            }
            __syncthreads();
        }
    }
    // exact recompute for head slots within QMARGIN of the 32nd approx key
    const unsigned a32q = sk[TOPK - 1] >> QSH;
    const unsigned cutq = a32q > QMARGIN ? a32q - QMARGIN : 0u;
    const int sub = tid & 3, ci = tid >> 2;
    #pragma unroll
    for (int base = 0; base < FINEN; base += 64) {
        int i = base + ci;
        unsigned key = sk[i];
        bool act = (key != 0u) && ((key >> QSH) >= cutq);
        int c = (int)(~key & QMASK);
        float s = 0.f;
        if (act) {
            const float4* k4 = reinterpret_cast<const float4*>(Kg + (size_t)c * DDIM) + sub;
            const float4* q4 = reinterpret_cast<const float4*>(qv) + sub;
            #pragma unroll
            for (int d = 0; d < 8; ++d) {
                float4 kk = k4[d * 4];
                float4 qq = q4[d * 4];
                s = fmaf(qq.x, kk.x, s); s = fmaf(qq.y, kk.y, s);
                s = fmaf(qq.z, kk.z, s); s = fmaf(qq.w, kk.w, s);
            }
        }
        s += __shfl_xor(s, 1); s += __shfl_xor(s, 2);
        if (act && sub == 0) {
            float dist = 2.0f - 2.0f * s;              // reference op order
            float rbf = expf(dist * -2.0f);            // exp(-dist/(2*0.25))
            sk64[i] = ((unsigned long long)__float_as_uint(rbf) << 32)
                    | (unsigned)(~(unsigned)c);        // rbf desc, then idx asc
        }
    }
    __syncthreads();
    // bitonic sort u64 desc, 256 elems, 256 threads (1 CE owner per pair)
    for (int k = 2; k <= FINEN; k <<= 1) {
        for (int j = k >> 1; j > 0; j >>= 1) {
            int x = tid ^ j;
            if (x > tid) {
                unsigned long long a = sk64[tid], b = sk64[x];
                bool sw = ((tid & k) == 0) ? (a < b) : (a > b);
                if (sw) { sk64[tid] = b; sk64[x] = a; }
            }
            __syncthreads();
        }
    }
    if (tid < TOPK) {
        unsigned long long kk = sk64[tid];
        float rbf = __uint_as_float((unsigned)(kk >> 32));
        int   idx = (int)(~(unsigned)kk);
        selV[tid] = rbf; selI[tid] = idx;
        float lw = logf(rbf + 1e-8f) + logf(hIn[idx] + 1e-8f);
        float mx = lw;
        #pragma unroll
        for (int o = 16; o > 0; o >>= 1) mx = fmaxf(mx, __shfl_xor(mx, o));
        float ex = expf(lw - mx);
        float sm = ex;
        #pragma unroll
        for (int o = 16; o > 0; o >>= 1) sm += __shfl_xor(sm, o);
        wts[tid] = ex / sm;
    }
    __syncthreads();
    {
        float acc = 0.f;
        const int v = tid;
        #pragma unroll
        for (int k = 0; k < TOPK; ++k)
            acc = fmaf(wts[k], V[(size_t)selI[k] * 256 + v], acc);
        out[(size_t)q * 256 + v] = acc;
    }
    const int offE = NQTOT * 256;
    const int offW = offE + NQTOT * 4;
    const int offI = offW + NQTOT * TOPK;
    if (tid < 4) {
        float acc = 0.f;
        #pragma unroll
        for (int k = 0; k < TOPK; ++k)
            acc = fmaf(wts[k], eIn[(size_t)selI[k] * 4 + tid], acc);
        out[offE + q * 4 + tid] = acc;
    }
    if (tid < TOPK) {
        out[offW + q * TOPK + tid] = wts[tid];
        out[offI + q * TOPK + tid] = (float)selI[tid];
    }
}

// ---------------------------------------------------------------------------
extern "C" void kernel_launch(void* const* d_in, const int* in_sizes, int n_in,
                              void* d_out, int out_size, void* d_ws, size_t ws_size,
                              hipStream_t stream)
{
    (void)n_in; (void)out_size; (void)ws_size;
    const float* Qg = (const float*)d_in[0];
    const float* Kg = (const float*)d_in[1];
    const float* Vg = (const float*)d_in[2];
    const float* hg = (const float*)d_in[3];
    const float* eg = (const float*)d_in[4];
    const int N = in_sizes[1] / DDIM;          // 100000

    char* w = (char*)d_ws;
    unsigned short* Kbf = (unsigned short*)w;  w += (size_t)N * DDIM * 2;      // 25.6MB
    unsigned short* Qbf = (unsigned short*)w;  w += (size_t)NQTOT * DDIM * 2;  // 256KB
    float* thr = (float*)w;                    w += NQTOT * 4;                 // 4KB
    int*   cnt2 = (int*)w;                     w += (size_t)NQTOT * NGRP * 4;  // 256KB
    unsigned char* binsU8 = (unsigned char*)w;                                 // 12.58MB
    unsigned int*  buckets = (unsigned int*)w; // aliases binsU8 (sequential lifetimes)

    hipMemsetAsync(cnt2, 0, (size_t)NQTOT * NGRP * 4, stream);

    dim3 blk(256);
    convert_kernel<<<dim3(2048), blk, 0, stream>>>(
        Qg, Kg, Qbf, Kbf, NQTOT * DDIM / 8, N * DDIM / 8);
    gemm_pass<0><<<dim3(MSAMPLE / 128, NQTOT / 128), blk, 0, stream>>>(
        Qbf, Kbf, N, binsU8, nullptr, nullptr, nullptr);
    thresh_kernel<<<dim3(NQTOT), blk, 0, stream>>>(binsU8, thr);
    gemm_pass<1><<<dim3(NGRP, NQTOT / 128), blk, 0, stream>>>(
        Qbf, Kbf, N, nullptr, thr, cnt2, buckets);
    finalize_kernel<<<dim3(NQTOT), blk, 0, stream>>>(
        buckets, cnt2, Qg, Kg, Vg, hg, eg, (float*)d_out, N);
}